// Round 1
// baseline (367.573 us; speedup 1.0000x reference)
//
#include <hip/hip_runtime.h>
#include <hip/hip_bf16.h>

// SMPL collapsed-form implementation.
// Sizes: B=1024, V=6890, NB=10, NJ=24, NP=207, NK=19.
constexpr int Vn    = 6890;
constexpr int VC3   = 20670;   // V*3
constexpr int QTOT  = 224;     // padded q rows: [ones, v_template, 10 shapedirs, 207 posedirs, 5 zero]
constexpr int NCOL  = 480;     // 456 (k,j) cols + 24 Jreg cols
constexpr int WROW  = 1440;    // NCOL*3
constexpr int MCOLS = 1368;    // 456*3

// ---------------- K0: build Dext (QTOT x VC3), Gext (V x NCOL), zero Wp ----------------
__global__ __launch_bounds__(256) void k0_build(
    const float* __restrict__ vt, const float* __restrict__ sdirs,
    const float* __restrict__ pdirs, const float* __restrict__ Jreg,
    const float* __restrict__ jreg, const float* __restrict__ wts,
    float* __restrict__ Dext, float* __restrict__ Gext, float* __restrict__ Wp)
{
    int bx = blockIdx.x;
    constexpr int BPR  = 81;          // blocks per Dext row (81*256 >= 20670)
    constexpr int DBLK = QTOT * BPR;  // 18144
    if (bx < DBLK) {
        int row = bx / BPR;
        int col = (bx % BPR) * 256 + threadIdx.x;
        if (col < VC3) {
            float val;
            if (row == 0)        val = 1.0f;
            else if (row == 1)   val = vt[col];
            else if (row < 12)   val = sdirs[(row - 2) * VC3 + col];
            else if (row < 219)  val = pdirs[(row - 12) * VC3 + col];
            else                 val = 0.0f;
            Dext[row * VC3 + col] = val;
        }
        return;
    }
    bx -= DBLK;
    if (bx < Vn) {
        int v = bx;
        for (int col = threadIdx.x; col < NCOL; col += 256) {
            float g;
            if (col < 456) {
                int k = col / 24, j = col % 24;
                g = jreg[v * 19 + k] * wts[v * 24 + j];
            } else {
                g = Jreg[v * 24 + (col - 456)];
            }
            Gext[v * NCOL + col] = g;
        }
        return;
    }
    bx -= Vn;
    int idx = bx * 256 + threadIdx.x;
    if (idx < QTOT * WROW) Wp[idx] = 0.0f;
}

// ---------------- K1: Wp[q][col*3+c] = sum_v Dext[q][3v+c] * Gext[v][col] ----------------
// fp32 vector GEMM, K split into 8 segments, atomicAdd into Wp (zeroed by K0).
__global__ __launch_bounds__(256) void k1_gemm(
    const float* __restrict__ Dext, const float* __restrict__ Gext,
    float* __restrict__ Wp)
{
    __shared__ float Ds[32][51];   // [qq][vv*3+c]  (48 used, padded to 51 vs bank conflicts)
    __shared__ float Gs[16][64];   // [vv][cc]
    int bx    = blockIdx.x;
    int ctile = bx & 7;            // 8 col tiles of 64
    int qtile = (bx >> 3) % 7;     // 7 q tiles of 32
    int kseg  = bx / 56;           // 8 K segments of 864
    int q0 = qtile * 32, c0 = ctile * 64;
    int v0 = kseg * 864;
    int v1 = v0 + 864; if (v1 > Vn) v1 = Vn;

    int tid = threadIdx.x;
    int tx = tid & 15, ty = tid >> 4;
    int ld_qq = tid >> 3;          // 0..31
    int ld_i0 = (tid & 7) * 6;     // 0..42
    int ld_vv = tid >> 4;          // 0..15
    int ld_cc = (tid & 15) * 4;    // 0..60

    float acc[2][4][3] = {};

    for (int v = v0; v < v1; v += 16) {
        {   // stage D tile: 32 q-rows x 48 floats
            const float* src = Dext + (q0 + ld_qq) * VC3 + 3 * v + ld_i0;
            int base = 3 * v + ld_i0;
            #pragma unroll
            for (int i = 0; i < 6; ++i)
                Ds[ld_qq][ld_i0 + i] = (base + i < VC3) ? src[i] : 0.0f;
        }
        {   // stage G tile: 16 v-rows x 64 cols
            int vg = v + ld_vv;
            float4 g = make_float4(0.f, 0.f, 0.f, 0.f);
            if (vg < Vn) {
                int cc = c0 + ld_cc;
                if (cc + 3 < NCOL) {
                    g = *(const float4*)(Gext + vg * NCOL + cc);
                } else {
                    float tmp[4] = {0.f, 0.f, 0.f, 0.f};
                    #pragma unroll
                    for (int i = 0; i < 4; ++i)
                        if (cc + i < NCOL) tmp[i] = Gext[vg * NCOL + cc + i];
                    g = make_float4(tmp[0], tmp[1], tmp[2], tmp[3]);
                }
            }
            *(float4*)&Gs[ld_vv][ld_cc] = g;
        }
        __syncthreads();
        #pragma unroll
        for (int vv = 0; vv < 16; ++vv) {
            float4 g = *(const float4*)&Gs[vv][tx * 4];
            #pragma unroll
            for (int qi = 0; qi < 2; ++qi) {
                float d0 = Ds[ty * 2 + qi][vv * 3 + 0];
                float d1 = Ds[ty * 2 + qi][vv * 3 + 1];
                float d2 = Ds[ty * 2 + qi][vv * 3 + 2];
                acc[qi][0][0] += d0 * g.x; acc[qi][0][1] += d1 * g.x; acc[qi][0][2] += d2 * g.x;
                acc[qi][1][0] += d0 * g.y; acc[qi][1][1] += d1 * g.y; acc[qi][1][2] += d2 * g.y;
                acc[qi][2][0] += d0 * g.z; acc[qi][2][1] += d1 * g.z; acc[qi][2][2] += d2 * g.z;
                acc[qi][3][0] += d0 * g.w; acc[qi][3][1] += d1 * g.w; acc[qi][3][2] += d2 * g.w;
            }
        }
        __syncthreads();
    }
    #pragma unroll
    for (int qi = 0; qi < 2; ++qi) {
        int q = q0 + ty * 2 + qi;
        #pragma unroll
        for (int ci = 0; ci < 4; ++ci) {
            int col = c0 + tx * 4 + ci;
            if (col < NCOL) {
                #pragma unroll
                for (int c = 0; c < 3; ++c)
                    atomicAdd(&Wp[q * WROW + col * 3 + c], acc[qi][ci][c]);
            }
        }
    }
}

// ---------------- K2: per-batch Rodrigues, J, kinematic chain, x-vector ----------------
__global__ __launch_bounds__(64) void k2_prep(
    const float* __restrict__ beta, const float* __restrict__ theta,
    const float* __restrict__ Wp,
    float* __restrict__ xmat, float* __restrict__ RAg, float* __restrict__ tAg)
{
    int b = blockIdx.x;
    int lane = threadIdx.x;
    __shared__ float Rs[24][9];
    __shared__ float Jl[24][3];
    __shared__ float resR[24][9];
    __shared__ float rest[24][3];
    __shared__ float bet[10];

    if (lane < 10) bet[lane] = beta[b * 10 + lane];
    if (lane < 24) {
        float t0 = theta[b * 72 + lane * 3 + 0];
        float t1 = theta[b * 72 + lane * 3 + 1];
        float t2 = theta[b * 72 + lane * 3 + 2];
        float e0 = t0 + 1e-8f, e1 = t1 + 1e-8f, e2 = t2 + 1e-8f;
        float angle = sqrtf(e0 * e0 + e1 * e1 + e2 * e2);
        float half = 0.5f * angle;
        float sh = sinf(half), ch = cosf(half);
        float s = sh / angle;
        float qx = t0 * s, qy = t1 * s, qz = t2 * s;
        float qn = sqrtf(ch * ch + qx * qx + qy * qy + qz * qz);
        float w = ch / qn, x = qx / qn, y = qy / qn, z = qz / qn;
        Rs[lane][0] = 1.f - 2.f * (y * y + z * z);
        Rs[lane][1] = 2.f * (x * y - w * z);
        Rs[lane][2] = 2.f * (x * z + w * y);
        Rs[lane][3] = 2.f * (x * y + w * z);
        Rs[lane][4] = 1.f - 2.f * (x * x + z * z);
        Rs[lane][5] = 2.f * (y * z - w * x);
        Rs[lane][6] = 2.f * (x * z - w * y);
        Rs[lane][7] = 2.f * (y * z + w * x);
        Rs[lane][8] = 1.f - 2.f * (x * x + y * y);
    }
    __syncthreads();
    // J[j][c] = W[1][(456+j)*3+c] + sum_n beta[n] * W[2+n][(456+j)*3+c]
    for (int idx = lane; idx < 72; idx += 64) {
        int j = idx / 3, c = idx % 3;
        const float* colp = Wp + (456 + j) * 3 + c;
        float acc = colp[1 * WROW];
        #pragma unroll
        for (int n = 0; n < 10; ++n) acc += bet[n] * colp[(2 + n) * WROW];
        Jl[j][c] = acc;
    }
    // x vector: [0, 1, beta(10), pose_feature(207), 0 pad]
    for (int q = lane; q < QTOT; q += 64) {
        float xv = 0.f;
        if (q == 1) xv = 1.f;
        else if (q >= 2 && q < 12) xv = bet[q - 2];
        else if (q >= 12 && q < 219) {
            int p = q - 12;
            int jj = 1 + p / 9, e = p % 9;
            float r = Rs[jj][e];
            if (e == 0 || e == 4 || e == 8) r -= 1.f;
            xv = r;
        }
        xmat[b * QTOT + q] = xv;
    }
    __syncthreads();
    if (lane == 0) {
        const int par[24] = {-1,0,0,0,1,2,3,4,5,6,7,8,9,9,9,12,13,14,16,17,18,19,20,21};
        #pragma unroll
        for (int r = 0; r < 3; ++r) {   // root: Rs[0] @ diag(1,-1,-1), t = J[0]
            resR[0][r * 3 + 0] =  Rs[0][r * 3 + 0];
            resR[0][r * 3 + 1] = -Rs[0][r * 3 + 1];
            resR[0][r * 3 + 2] = -Rs[0][r * 3 + 2];
            rest[0][r] = Jl[0][r];
        }
        for (int i = 1; i < 24; ++i) {
            int p = par[i];
            float t0 = Jl[i][0] - Jl[p][0];
            float t1 = Jl[i][1] - Jl[p][1];
            float t2 = Jl[i][2] - Jl[p][2];
            #pragma unroll
            for (int r = 0; r < 3; ++r) {
                float a0 = resR[p][r * 3 + 0], a1 = resR[p][r * 3 + 1], a2 = resR[p][r * 3 + 2];
                resR[i][r * 3 + 0] = a0 * Rs[i][0] + a1 * Rs[i][3] + a2 * Rs[i][6];
                resR[i][r * 3 + 1] = a0 * Rs[i][1] + a1 * Rs[i][4] + a2 * Rs[i][7];
                resR[i][r * 3 + 2] = a0 * Rs[i][2] + a1 * Rs[i][5] + a2 * Rs[i][8];
                rest[i][r] = a0 * t0 + a1 * t1 + a2 * t2 + rest[p][r];
            }
        }
    }
    __syncthreads();
    for (int idx = lane; idx < 216; idx += 64)
        RAg[b * 216 + idx] = resR[idx / 9][idx % 9];
    for (int idx = lane; idx < 72; idx += 64) {
        int j = idx / 3, c = idx % 3;
        tAg[b * 72 + idx] = rest[j][c]
            - (resR[j][c * 3 + 0] * Jl[j][0] + resR[j][c * 3 + 1] * Jl[j][1]
             + resR[j][c * 3 + 2] * Jl[j][2]);
    }
}

// ---------------- K3: M[b][colc] = sum_q xmat[b][q] * Wp[q][colc], colc < 1368 ----------------
__global__ __launch_bounds__(256) void k3_gemm(
    const float* __restrict__ xmat, const float* __restrict__ Wp,
    float* __restrict__ Mg)
{
    __shared__ float As[16][64];   // [k][b]
    __shared__ float Bs[16][64];   // [k][colc]
    int ct = blockIdx.x % 22;
    int bt = blockIdx.x / 22;
    int b0 = bt * 64, c0 = ct * 64;
    int tid = threadIdx.x;
    int tx = tid & 15, ty = tid >> 4;
    int a_b = tid & 63, a_k = (tid >> 6) * 4;
    int b_k = tid >> 4, b_c = (tid & 15) * 4;
    float acc[4][4] = {};

    for (int k0 = 0; k0 < QTOT; k0 += 16) {
        float4 av = *(const float4*)(xmat + (b0 + a_b) * QTOT + k0 + a_k);
        As[a_k + 0][a_b] = av.x; As[a_k + 1][a_b] = av.y;
        As[a_k + 2][a_b] = av.z; As[a_k + 3][a_b] = av.w;
        *(float4*)&Bs[b_k][b_c] = *(const float4*)(Wp + (k0 + b_k) * WROW + c0 + b_c);
        __syncthreads();
        #pragma unroll
        for (int kk = 0; kk < 16; ++kk) {
            float4 a4 = *(const float4*)&As[kk][ty * 4];
            float4 b4 = *(const float4*)&Bs[kk][tx * 4];
            acc[0][0] += a4.x * b4.x; acc[0][1] += a4.x * b4.y; acc[0][2] += a4.x * b4.z; acc[0][3] += a4.x * b4.w;
            acc[1][0] += a4.y * b4.x; acc[1][1] += a4.y * b4.y; acc[1][2] += a4.y * b4.z; acc[1][3] += a4.y * b4.w;
            acc[2][0] += a4.z * b4.x; acc[2][1] += a4.z * b4.y; acc[2][2] += a4.z * b4.z; acc[2][3] += a4.z * b4.w;
            acc[3][0] += a4.w * b4.x; acc[3][1] += a4.w * b4.y; acc[3][2] += a4.w * b4.z; acc[3][3] += a4.w * b4.w;
        }
        __syncthreads();
    }
    #pragma unroll
    for (int i = 0; i < 4; ++i) {
        int bb = b0 + ty * 4 + i;
        #pragma unroll
        for (int j = 0; j < 4; ++j) {
            int cc = c0 + tx * 4 + j;
            if (cc < MCOLS) Mg[bb * MCOLS + cc] = acc[i][j];
        }
    }
}

// ---------------- K4: joints[b][k][c] = trans + sum_j RA[c,:].M + tA[c]*w1 ----------------
__global__ __launch_bounds__(256) void k4_combine(
    const float* __restrict__ Mg, const float* __restrict__ RAg,
    const float* __restrict__ tAg, const float* __restrict__ Wp,
    const float* __restrict__ trans, float* __restrict__ out)
{
    __shared__ float w1s[456];
    __shared__ float Ms[4 * 1368];
    __shared__ float RAs[4 * 216];
    __shared__ float tAs[4 * 72];
    int tid = threadIdx.x;
    int b0 = blockIdx.x * 4;
    for (int i = tid; i < 456; i += 256) w1s[i] = Wp[i * 3];  // ones-row of W
    for (int i = tid; i < 4 * 1368; i += 256) Ms[i] = Mg[b0 * MCOLS + i];
    for (int i = tid; i < 4 * 216; i += 256) RAs[i] = RAg[b0 * 216 + i];
    for (int i = tid; i < 4 * 72; i += 256) tAs[i] = tAg[b0 * 72 + i];
    __syncthreads();
    if (tid < 228) {
        int lb = tid / 57, kc = tid % 57;
        int k = kc / 3, c = kc % 3;
        int b = b0 + lb;
        float acc = trans[b * 3 + c];
        const float* Mrow = Ms + lb * 1368;
        const float* RAr  = RAs + lb * 216;
        const float* tAr  = tAs + lb * 72;
        #pragma unroll
        for (int j = 0; j < 24; ++j) {
            int kj = k * 24 + j;
            float m0 = Mrow[kj * 3 + 0], m1 = Mrow[kj * 3 + 1], m2 = Mrow[kj * 3 + 2];
            acc += RAr[j * 9 + c * 3 + 0] * m0
                 + RAr[j * 9 + c * 3 + 1] * m1
                 + RAr[j * 9 + c * 3 + 2] * m2
                 + tAr[j * 3 + c] * w1s[kj];
        }
        out[b * 57 + kc] = acc;
    }
}

extern "C" void kernel_launch(void* const* d_in, const int* in_sizes, int n_in,
                              void* d_out, int out_size, void* d_ws, size_t ws_size,
                              hipStream_t stream)
{
    const float* beta  = (const float*)d_in[0];
    const float* theta = (const float*)d_in[1];
    const float* trans = (const float*)d_in[2];
    const float* vt    = (const float*)d_in[3];
    const float* sdirs = (const float*)d_in[4];
    const float* Jreg  = (const float*)d_in[5];
    const float* pdirs = (const float*)d_in[6];
    const float* jreg  = (const float*)d_in[7];
    const float* wts   = (const float*)d_in[8];
    float* out = (float*)d_out;
    int B = in_sizes[0] / 10;   // 1024

    // workspace layout (floats); total ~10.2M floats = ~41 MB
    float* ws   = (float*)d_ws;
    float* Dext = ws;                                   // QTOT*VC3
    float* Gext = Dext + (size_t)QTOT * VC3;            // Vn*NCOL
    float* Wp   = Gext + (size_t)Vn * NCOL;             // QTOT*WROW
    float* xmat = Wp + (size_t)QTOT * WROW;             // B*QTOT
    float* RAg  = xmat + (size_t)B * QTOT;              // B*216
    float* tAg  = RAg + (size_t)B * 216;                // B*72
    float* Mg   = tAg + (size_t)B * 72;                 // B*MCOLS

    k0_build<<<dim3(QTOT * 81 + Vn + 1260), 256, 0, stream>>>(
        vt, sdirs, pdirs, Jreg, jreg, wts, Dext, Gext, Wp);
    k1_gemm<<<dim3(448), 256, 0, stream>>>(Dext, Gext, Wp);
    k2_prep<<<dim3(B), 64, 0, stream>>>(beta, theta, Wp, xmat, RAg, tAg);
    k3_gemm<<<dim3((B / 64) * 22), 256, 0, stream>>>(xmat, Wp, Mg);
    k4_combine<<<dim3(B / 4), 256, 0, stream>>>(Mg, RAg, tAg, Wp, trans, out);
}

// Round 2
// 181.189 us; speedup vs baseline: 2.0287x; 2.0287x over previous
//
#include <hip/hip_runtime.h>
#include <hip/hip_bf16.h>

// SMPL collapsed-form, bf16-MFMA version.
// B=1024, V=6890, NB=10, NJ=24, NP=207, NK=19.
constexpr int Vn   = 6890;
constexpr int VC3  = 20670;   // V*3
constexpr int KP   = 6912;    // padded K (V) for MFMA, mult of 64
constexpr int QT   = 224;     // q rows: [ones, v_template, 10 shapedirs, 207 posedirs, 5 zero]
constexpr int QP   = 256;     // padded q rows in Ab (rows 224..255 zero)
constexpr int NCOL = 480;     // 456 (k,j) cols + 24 Jreg cols
constexpr int NCP  = 512;     // padded cols in Gt
constexpr int WR   = 1440;    // W rows in transposed layout = 480*3
constexpr int MC   = 1368;    // 456*3
constexpr int KSEG = 6;       // K split for k1 (6912/6 = 1152 = 18*64)

using bf16x8  = __attribute__((ext_vector_type(8))) short;
using floatx4 = __attribute__((ext_vector_type(4))) float;

__device__ __forceinline__ unsigned short f2bf(float f) {
    unsigned int u = __float_as_uint(f);
    unsigned int r = (u + 0x7FFFu + ((u >> 16) & 1u)) >> 16;
    return (unsigned short)r;
}

__device__ __forceinline__ void async16(void* lds, const void* g) {
    __builtin_amdgcn_global_load_lds(
        (const __attribute__((address_space(1))) void*)g,
        (__attribute__((address_space(3))) void*)lds, 16, 0, 0);
}

// ---------- K0: build Ab [3][QP][KP] bf16, Gt [NCP][KP] bf16, zero WtF ----------
__global__ __launch_bounds__(256) void k0_build(
    const float* __restrict__ vt, const float* __restrict__ sdirs,
    const float* __restrict__ pdirs, const float* __restrict__ Jreg,
    const float* __restrict__ jreg, const float* __restrict__ wts,
    unsigned short* __restrict__ Ab, unsigned short* __restrict__ Gt,
    float* __restrict__ WtF)
{
    int bx = blockIdx.x, t = threadIdx.x;
    if (bx < QP * 27) {                      // ---- part A: Ab planes
        int q = bx / 27, v0 = (bx % 27) * 256;
        __shared__ float s[768];
        const float* src = nullptr;
        if (q == 1) src = vt;
        else if (q >= 2 && q < 12)   src = sdirs + (q - 2) * VC3;
        else if (q >= 12 && q < 219) src = pdirs + (q - 12) * VC3;
        #pragma unroll
        for (int i = 0; i < 3; ++i) {
            int idx = 3 * v0 + t + 256 * i;
            float val = 0.f;
            if (idx < VC3) {
                if (q == 0) val = 1.f;
                else if (src) val = src[idx];
            }
            s[t + 256 * i] = val;
        }
        __syncthreads();
        #pragma unroll
        for (int c = 0; c < 3; ++c)
            Ab[((size_t)c * QP + q) * KP + v0 + t] = f2bf(s[3 * t + c]);
        return;
    }
    bx -= QP * 27;
    if (bx < 108) {                          // ---- part B: Gt
        int v0 = bx * 64;
        __shared__ float js[64 * 19], wsh[64 * 25], Jsh[64 * 25];
        for (int i = t; i < 64 * 19; i += 256)
            js[i] = (v0 * 19 + i < Vn * 19) ? jreg[v0 * 19 + i] : 0.f;
        for (int i = t; i < 64 * 24; i += 256) {
            float x = (v0 * 24 + i < Vn * 24) ? wts[v0 * 24 + i] : 0.f;
            wsh[(i / 24) * 25 + i % 24] = x;
        }
        for (int i = t; i < 64 * 24; i += 256) {
            float x = (v0 * 24 + i < Vn * 24) ? Jreg[v0 * 24 + i] : 0.f;
            Jsh[(i / 24) * 25 + i % 24] = x;
        }
        __syncthreads();
        int v = t & 63, cg = t >> 6;
        for (int p = 0; p < 128; ++p) {
            int col = p * 4 + cg;
            float val = 0.f;
            if (col < 456)       val = js[v * 19 + col / 24] * wsh[v * 25 + col % 24];
            else if (col < 480)  val = Jsh[v * 25 + (col - 456)];
            Gt[(size_t)col * KP + v0 + v] = f2bf(val);
        }
        return;
    }
    bx -= 108;                               // ---- part C: zero WtF
    int idx = bx * 256 + t;
    if (idx < WR * QT) WtF[idx] = 0.f;
}

// ---------- K1: WtF[(col*3+c)][q] += sum_v A_c[q][v] * Gt[col][v]  (bf16 MFMA) ----------
__global__ __launch_bounds__(256) void k1_mfma(
    const unsigned short* __restrict__ Ab, const unsigned short* __restrict__ Gt,
    float* __restrict__ WtF)
{
    __shared__ __align__(16) unsigned short lA[4096];  // 8 frags x 1KB
    __shared__ __align__(16) unsigned short lB[4096];
    int bx = blockIdx.x;
    int kseg = bx % KSEG; int tmp = bx / KSEG;
    int c  = tmp % 3; tmp /= 3;
    int ct = tmp & 7, qt = tmp >> 3;
    int q0 = qt * 64, c0 = ct * 64, kb0 = kseg * (KP / KSEG);
    int tid = threadIdx.x, w = tid >> 6, l = tid & 63;
    int lr = l & 15, lk8 = (l >> 4) * 8;
    int wm = w & 1, wn = w >> 1;

    const unsigned short* gA = Ab + ((size_t)c * QP + q0 + w * 16 + lr) * KP + kb0 + lk8;
    const unsigned short* gB = Gt + ((size_t)(c0 + w * 16 + lr)) * KP + kb0 + lk8;

    floatx4 acc00 = {0,0,0,0}, acc01 = {0,0,0,0}, acc10 = {0,0,0,0}, acc11 = {0,0,0,0};

    unsigned short* sA0 = &lA[(0 + w) * 512];
    unsigned short* sA1 = &lA[(4 + w) * 512];
    unsigned short* sB0 = &lB[(0 + w) * 512];
    unsigned short* sB1 = &lB[(4 + w) * 512];

    for (int it = 0; it < (KP / KSEG) / 64; ++it) {
        int ko = it * 64;
        async16(sA0, gA + ko);      async16(sA1, gA + ko + 32);
        async16(sB0, gB + ko);      async16(sB1, gB + ko + 32);
        __syncthreads();
        {   // kk = 0
            bf16x8 a0 = *(const bf16x8*)&lA[(wm * 2 + 0) * 512 + l * 8];
            bf16x8 a1 = *(const bf16x8*)&lA[(wm * 2 + 1) * 512 + l * 8];
            bf16x8 b0 = *(const bf16x8*)&lB[(wn * 2 + 0) * 512 + l * 8];
            bf16x8 b1 = *(const bf16x8*)&lB[(wn * 2 + 1) * 512 + l * 8];
            acc00 = __builtin_amdgcn_mfma_f32_16x16x32_bf16(a0, b0, acc00, 0, 0, 0);
            acc01 = __builtin_amdgcn_mfma_f32_16x16x32_bf16(a0, b1, acc01, 0, 0, 0);
            acc10 = __builtin_amdgcn_mfma_f32_16x16x32_bf16(a1, b0, acc10, 0, 0, 0);
            acc11 = __builtin_amdgcn_mfma_f32_16x16x32_bf16(a1, b1, acc11, 0, 0, 0);
        }
        {   // kk = 1
            bf16x8 a0 = *(const bf16x8*)&lA[(4 + wm * 2 + 0) * 512 + l * 8];
            bf16x8 a1 = *(const bf16x8*)&lA[(4 + wm * 2 + 1) * 512 + l * 8];
            bf16x8 b0 = *(const bf16x8*)&lB[(4 + wn * 2 + 0) * 512 + l * 8];
            bf16x8 b1 = *(const bf16x8*)&lB[(4 + wn * 2 + 1) * 512 + l * 8];
            acc00 = __builtin_amdgcn_mfma_f32_16x16x32_bf16(a0, b0, acc00, 0, 0, 0);
            acc01 = __builtin_amdgcn_mfma_f32_16x16x32_bf16(a0, b1, acc01, 0, 0, 0);
            acc10 = __builtin_amdgcn_mfma_f32_16x16x32_bf16(a1, b0, acc10, 0, 0, 0);
            acc11 = __builtin_amdgcn_mfma_f32_16x16x32_bf16(a1, b1, acc11, 0, 0, 0);
        }
        __syncthreads();
    }
    int r0 = (l >> 4) * 4;
    const floatx4* accs[2][2] = {{&acc00, &acc01}, {&acc10, &acc11}};
    #pragma unroll
    for (int mi = 0; mi < 2; ++mi)
        #pragma unroll
        for (int ni = 0; ni < 2; ++ni) {
            int col = c0 + wn * 32 + ni * 16 + lr;
            #pragma unroll
            for (int r = 0; r < 4; ++r) {
                int q = q0 + wm * 32 + mi * 16 + r0 + r;
                if (q < QT && col < NCOL)
                    atomicAdd(&WtF[((size_t)col * 3 + c) * QT + q], (*accs[mi][ni])[r]);
            }
        }
}

// ---------- K2: per-batch Rodrigues, J, kinematic chain, x-vector (bf16) ----------
__global__ __launch_bounds__(64) void k2_prep(
    const float* __restrict__ beta, const float* __restrict__ theta,
    const float* __restrict__ WtF,
    unsigned short* __restrict__ xb, float* __restrict__ RAg, float* __restrict__ tAg)
{
    int b = blockIdx.x;
    int lane = threadIdx.x;
    __shared__ float Rs[24][9];
    __shared__ float Jl[24][3];
    __shared__ float resR[24][9];
    __shared__ float rest[24][3];
    __shared__ float bet[10];

    if (lane < 10) bet[lane] = beta[b * 10 + lane];
    if (lane < 24) {
        float t0 = theta[b * 72 + lane * 3 + 0];
        float t1 = theta[b * 72 + lane * 3 + 1];
        float t2 = theta[b * 72 + lane * 3 + 2];
        float e0 = t0 + 1e-8f, e1 = t1 + 1e-8f, e2 = t2 + 1e-8f;
        float angle = sqrtf(e0 * e0 + e1 * e1 + e2 * e2);
        float half = 0.5f * angle;
        float sh = sinf(half), ch = cosf(half);
        float s = sh / angle;
        float qx = t0 * s, qy = t1 * s, qz = t2 * s;
        float qn = sqrtf(ch * ch + qx * qx + qy * qy + qz * qz);
        float w = ch / qn, x = qx / qn, y = qy / qn, z = qz / qn;
        Rs[lane][0] = 1.f - 2.f * (y * y + z * z);
        Rs[lane][1] = 2.f * (x * y - w * z);
        Rs[lane][2] = 2.f * (x * z + w * y);
        Rs[lane][3] = 2.f * (x * y + w * z);
        Rs[lane][4] = 1.f - 2.f * (x * x + z * z);
        Rs[lane][5] = 2.f * (y * z - w * x);
        Rs[lane][6] = 2.f * (x * z - w * y);
        Rs[lane][7] = 2.f * (y * z + w * x);
        Rs[lane][8] = 1.f - 2.f * (x * x + y * y);
    }
    __syncthreads();
    // J[j][c] = WtF[((456+j)*3+c)][1] + sum_n beta[n] * WtF[...][2+n]
    for (int idx = lane; idx < 72; idx += 64) {
        int j = idx / 3, c = idx % 3;
        const float* colp = WtF + (size_t)((456 + j) * 3 + c) * QT;
        float acc = colp[1];
        #pragma unroll
        for (int n = 0; n < 10; ++n) acc += bet[n] * colp[2 + n];
        Jl[j][c] = acc;
    }
    // x vector: [0, 1, beta(10), pose_feature(207), 0 pad] -> bf16
    for (int q = lane; q < QT; q += 64) {
        float xv = 0.f;
        if (q == 1) xv = 1.f;
        else if (q >= 2 && q < 12) xv = bet[q - 2];
        else if (q >= 12 && q < 219) {
            int p = q - 12;
            int jj = 1 + p / 9, e = p % 9;
            float r = Rs[jj][e];
            if (e == 0 || e == 4 || e == 8) r -= 1.f;
            xv = r;
        }
        xb[(size_t)b * QT + q] = f2bf(xv);
    }
    __syncthreads();
    if (lane == 0) {
        const int par[24] = {-1,0,0,0,1,2,3,4,5,6,7,8,9,9,9,12,13,14,16,17,18,19,20,21};
        #pragma unroll
        for (int r = 0; r < 3; ++r) {
            resR[0][r * 3 + 0] =  Rs[0][r * 3 + 0];
            resR[0][r * 3 + 1] = -Rs[0][r * 3 + 1];
            resR[0][r * 3 + 2] = -Rs[0][r * 3 + 2];
            rest[0][r] = Jl[0][r];
        }
        for (int i = 1; i < 24; ++i) {
            int p = par[i];
            float t0 = Jl[i][0] - Jl[p][0];
            float t1 = Jl[i][1] - Jl[p][1];
            float t2 = Jl[i][2] - Jl[p][2];
            #pragma unroll
            for (int r = 0; r < 3; ++r) {
                float a0 = resR[p][r * 3 + 0], a1 = resR[p][r * 3 + 1], a2 = resR[p][r * 3 + 2];
                resR[i][r * 3 + 0] = a0 * Rs[i][0] + a1 * Rs[i][3] + a2 * Rs[i][6];
                resR[i][r * 3 + 1] = a0 * Rs[i][1] + a1 * Rs[i][4] + a2 * Rs[i][7];
                resR[i][r * 3 + 2] = a0 * Rs[i][2] + a1 * Rs[i][5] + a2 * Rs[i][8];
                rest[i][r] = a0 * t0 + a1 * t1 + a2 * t2 + rest[p][r];
            }
        }
    }
    __syncthreads();
    for (int idx = lane; idx < 216; idx += 64)
        RAg[(size_t)b * 216 + idx] = resR[idx / 9][idx % 9];
    for (int idx = lane; idx < 72; idx += 64) {
        int j = idx / 3, c = idx % 3;
        tAg[(size_t)b * 72 + idx] = rest[j][c]
            - (resR[j][c * 3 + 0] * Jl[j][0] + resR[j][c * 3 + 1] * Jl[j][1]
             + resR[j][c * 3 + 2] * Jl[j][2]);
    }
}

// ---------- K3: Mg[b][cc] = sum_q xb[b][q] * W[q][cc]  (bf16 MFMA, K fits LDS) ----------
__global__ __launch_bounds__(256) void k3_mfma(
    const unsigned short* __restrict__ xb, const float* __restrict__ WtF,
    float* __restrict__ Mg)
{
    __shared__ __align__(16) unsigned short lA[28 * 512];   // 28KB: 4 mt x 7 kk frags
    __shared__ __align__(16) unsigned short lB[28 * 512];   // 28KB: 4 nt x 7 kk frags
    int bt = blockIdx.x / 22, ct = blockIdx.x % 22;
    int b0 = bt * 64, c0 = ct * 64;
    int tid = threadIdx.x, w = tid >> 6, l = tid & 63;
    int lr = l & 15, lk8 = (l >> 4) * 8;
    int wm = w & 1, wn = w >> 1;

    const unsigned short* gA = xb + (size_t)(b0 + w * 16 + lr) * QT + lk8;
    #pragma unroll
    for (int r = 0; r < 7; ++r)
        async16(&lA[(r * 4 + w) * 512], gA + r * 32);

    for (int s = tid; s < 64 * QT; s += 256) {
        int cl = s / QT, q = s - cl * QT;
        float v = WtF[(size_t)(c0 + cl) * QT + q];
        int nt = cl >> 4, n = cl & 15, kki = q >> 5, hi = (q >> 3) & 3, j = q & 7;
        lB[(kki * 4 + nt) * 512 + (hi * 16 + n) * 8 + j] = f2bf(v);
    }
    __syncthreads();

    floatx4 acc00 = {0,0,0,0}, acc01 = {0,0,0,0}, acc10 = {0,0,0,0}, acc11 = {0,0,0,0};
    #pragma unroll
    for (int kk = 0; kk < 7; ++kk) {
        bf16x8 a0 = *(const bf16x8*)&lA[(kk * 4 + wm * 2 + 0) * 512 + l * 8];
        bf16x8 a1 = *(const bf16x8*)&lA[(kk * 4 + wm * 2 + 1) * 512 + l * 8];
        bf16x8 b0 = *(const bf16x8*)&lB[(kk * 4 + wn * 2 + 0) * 512 + l * 8];
        bf16x8 b1 = *(const bf16x8*)&lB[(kk * 4 + wn * 2 + 1) * 512 + l * 8];
        acc00 = __builtin_amdgcn_mfma_f32_16x16x32_bf16(a0, b0, acc00, 0, 0, 0);
        acc01 = __builtin_amdgcn_mfma_f32_16x16x32_bf16(a0, b1, acc01, 0, 0, 0);
        acc10 = __builtin_amdgcn_mfma_f32_16x16x32_bf16(a1, b0, acc10, 0, 0, 0);
        acc11 = __builtin_amdgcn_mfma_f32_16x16x32_bf16(a1, b1, acc11, 0, 0, 0);
    }
    int r0 = (l >> 4) * 4;
    const floatx4* accs[2][2] = {{&acc00, &acc01}, {&acc10, &acc11}};
    #pragma unroll
    for (int mi = 0; mi < 2; ++mi)
        #pragma unroll
        for (int ni = 0; ni < 2; ++ni) {
            int cc = c0 + wn * 32 + ni * 16 + lr;
            if (cc < MC) {
                #pragma unroll
                for (int r = 0; r < 4; ++r) {
                    int b = b0 + wm * 32 + mi * 16 + r0 + r;
                    Mg[(size_t)b * MC + cc] = (*accs[mi][ni])[r];
                }
            }
        }
}

// ---------- K4: joints[b][k][c] = trans + sum_j RA[c,:].M + tA[c]*w1 ----------
__global__ __launch_bounds__(256) void k4_combine(
    const float* __restrict__ Mg, const float* __restrict__ RAg,
    const float* __restrict__ tAg, const float* __restrict__ WtF,
    const float* __restrict__ trans, float* __restrict__ out)
{
    __shared__ float w1s[456];
    __shared__ float Ms[4 * MC];
    __shared__ float RAs[4 * 216];
    __shared__ float tAs[4 * 72];
    int tid = threadIdx.x;
    int b0 = blockIdx.x * 4;
    for (int i = tid; i < 456; i += 256) w1s[i] = WtF[(size_t)i * 3 * QT];
    for (int i = tid; i < 4 * MC; i += 256) Ms[i] = Mg[(size_t)b0 * MC + i];
    for (int i = tid; i < 4 * 216; i += 256) RAs[i] = RAg[(size_t)b0 * 216 + i];
    for (int i = tid; i < 4 * 72; i += 256) tAs[i] = tAg[(size_t)b0 * 72 + i];
    __syncthreads();
    if (tid < 228) {
        int lb = tid / 57, kc = tid % 57;
        int k = kc / 3, c = kc % 3;
        int b = b0 + lb;
        float acc = trans[b * 3 + c];
        const float* Mrow = Ms + lb * MC;
        const float* RAr  = RAs + lb * 216;
        const float* tAr  = tAs + lb * 72;
        #pragma unroll
        for (int j = 0; j < 24; ++j) {
            int kj = k * 24 + j;
            float m0 = Mrow[kj * 3 + 0], m1 = Mrow[kj * 3 + 1], m2 = Mrow[kj * 3 + 2];
            acc += RAr[j * 9 + c * 3 + 0] * m0
                 + RAr[j * 9 + c * 3 + 1] * m1
                 + RAr[j * 9 + c * 3 + 2] * m2
                 + tAr[j * 3 + c] * w1s[kj];
        }
        out[b * 57 + kc] = acc;
    }
}

extern "C" void kernel_launch(void* const* d_in, const int* in_sizes, int n_in,
                              void* d_out, int out_size, void* d_ws, size_t ws_size,
                              hipStream_t stream)
{
    const float* beta  = (const float*)d_in[0];
    const float* theta = (const float*)d_in[1];
    const float* trans = (const float*)d_in[2];
    const float* vt    = (const float*)d_in[3];
    const float* sdirs = (const float*)d_in[4];
    const float* Jreg  = (const float*)d_in[5];
    const float* pdirs = (const float*)d_in[6];
    const float* jreg  = (const float*)d_in[7];
    const float* wts   = (const float*)d_in[8];
    float* out = (float*)d_out;
    int B = in_sizes[0] / 10;   // 1024

    // workspace layout (~26.3 MB)
    unsigned short* Ab = (unsigned short*)d_ws;                  // 3*QP*KP bf16
    unsigned short* Gt = Ab + (size_t)3 * QP * KP;               // NCP*KP bf16
    float* WtF = (float*)(Gt + (size_t)NCP * KP);                // WR*QT f32
    unsigned short* xb = (unsigned short*)(WtF + (size_t)WR * QT); // B*QT bf16
    float* RAg = (float*)(xb + (size_t)B * QT);                  // B*216
    float* tAg = RAg + (size_t)B * 216;                          // B*72
    float* Mg  = tAg + (size_t)B * 72;                           // B*MC

    k0_build<<<dim3(QP * 27 + 108 + 1260), 256, 0, stream>>>(
        vt, sdirs, pdirs, Jreg, jreg, wts, Ab, Gt, WtF);
    k1_mfma<<<dim3(4 * 8 * 3 * KSEG), 256, 0, stream>>>(Ab, Gt, WtF);
    k2_prep<<<dim3(B), 64, 0, stream>>>(beta, theta, WtF, xb, RAg, tAg);
    k3_mfma<<<dim3((B / 64) * 22), 256, 0, stream>>>(xb, WtF, Mg);
    k4_combine<<<dim3(B / 4), 256, 0, stream>>>(Mg, RAg, tAg, WtF, trans, out);
}

// Round 3
// 153.629 us; speedup vs baseline: 2.3926x; 1.1794x over previous
//
#include <hip/hip_runtime.h>
#include <hip/hip_bf16.h>

// SMPL collapsed-form, register-fragment MFMA version (no LDS in GEMMs).
// B=1024, V=6890, NB=10, NJ=24, NP=207, NK=19.
constexpr int Vn   = 6890;
constexpr int VC3  = 20670;   // V*3
constexpr int KP   = 6912;    // padded K (V), 216 k-blocks of 32
constexpr int NKB  = 216;     // KP/32
constexpr int QT   = 224;     // q rows: [ones, v_template, 10 shapedirs, 207 posedirs, 5 zero]
constexpr int NMG  = 14;      // QT/16 m-frag groups
constexpr int NCOL = 480;     // 456 (k,j) cols + 24 Jreg cols
constexpr int WR   = 1440;    // W rows transposed = 480*3
constexpr int MC   = 1368;    // 456*3
constexpr int KSEG = 8;       // K split for k1 (216/8 = 27 kb per wave)
constexpr int NG3  = 88;      // Wb3 col-frag groups (1408/16)

using bf16x8  = __attribute__((ext_vector_type(8))) short;
using floatx4 = __attribute__((ext_vector_type(4))) float;

__device__ __forceinline__ unsigned short f2bf(float f) {
    unsigned int u = __float_as_uint(f);
    unsigned int r = (u + 0x7FFFu + ((u >> 16) & 1u)) >> 16;
    return (unsigned short)r;
}

// ---------- K0: build Af [3][14][216] frags, Bf [32][216] frags ----------
// frag element (lane l, j): row = base + (l&15), k = kb*32 + (l>>4)*8 + j
__global__ __launch_bounds__(256) void k0_build(
    const float* __restrict__ vt, const float* __restrict__ sdirs,
    const float* __restrict__ pdirs, const float* __restrict__ Jreg,
    const float* __restrict__ jreg, const float* __restrict__ wts,
    unsigned short* __restrict__ Af, unsigned short* __restrict__ Bf)
{
    int bx = blockIdx.x, t = threadIdx.x;
    if (bx < QT * 27) {                       // ---- part A
        int q = bx / 27, v = (bx % 27) * 256 + t;
        float f[3] = {0.f, 0.f, 0.f};
        if (v < Vn) {
            if (q == 0) { f[0] = f[1] = f[2] = 1.f; }
            else {
                const float* src = nullptr;
                if (q == 1) src = vt;
                else if (q >= 2 && q < 12)   src = sdirs + (size_t)(q - 2) * VC3;
                else if (q >= 12 && q < 219) src = pdirs + (size_t)(q - 12) * VC3;
                if (src) { f[0] = src[3 * v]; f[1] = src[3 * v + 1]; f[2] = src[3 * v + 2]; }
            }
        }
        int mg = q >> 4, kb = v >> 5;
        size_t off = (size_t)((q & 15) + ((v >> 3) & 3) * 16) * 8 + (v & 7);
        #pragma unroll
        for (int c = 0; c < 3; ++c)
            Af[((size_t)(c * NMG + mg) * NKB + kb) * 512 + off] = f2bf(f[c]);
        return;
    }
    bx -= QT * 27;                            // ---- part B (108 blocks, 64 v each)
    int v0 = bx * 64;
    __shared__ float js[64 * 19], wsh[64 * 24], Jsh[64 * 24];
    for (int i = t; i < 64 * 19; i += 256)
        js[i] = (v0 * 19 + i < Vn * 19) ? jreg[v0 * 19 + i] : 0.f;
    for (int i = t; i < 64 * 24; i += 256) {
        wsh[i] = (v0 * 24 + i < Vn * 24) ? wts[v0 * 24 + i] : 0.f;
        Jsh[i] = (v0 * 24 + i < Vn * 24) ? Jreg[v0 * 24 + i] : 0.f;
    }
    __syncthreads();
    for (int s = t; s < 4096; s += 256) {     // 512 cols x 8 v-groups
        int col = s >> 3, vg = s & 7;
        int kb = (v0 >> 5) + (vg >> 2);
        bf16x8 o;
        #pragma unroll
        for (int j = 0; j < 8; ++j) {
            int vl = vg * 8 + j;
            float val = 0.f;
            if (col < 456)      val = js[vl * 19 + col / 24] * wsh[vl * 24 + col % 24];
            else if (col < 480) val = Jsh[vl * 24 + (col - 456)];
            o[j] = (short)f2bf(val);
        }
        *(bf16x8*)(Bf + ((size_t)(col >> 4) * NKB + kb) * 512
                      + (size_t)((col & 15) + (vg & 3) * 16) * 8) = o;
    }
}

// ---------- K1: register-fragment MFMA GEMM, no LDS, no barriers ----------
// wave tile: 32q x 64col, K chunk = 27 kb (864). Output: P[kseg][colc][q].
__device__ __forceinline__ void k1_load(bf16x8 (&a)[2], bf16x8 (&b)[4],
    const unsigned short* __restrict__ ap, const unsigned short* __restrict__ bp, int i)
{
    a[0] = *(const bf16x8*)(ap + (size_t)(0 * NKB + i) * 512);
    a[1] = *(const bf16x8*)(ap + (size_t)(1 * NKB + i) * 512);
    b[0] = *(const bf16x8*)(bp + (size_t)(0 * NKB + i) * 512);
    b[1] = *(const bf16x8*)(bp + (size_t)(1 * NKB + i) * 512);
    b[2] = *(const bf16x8*)(bp + (size_t)(2 * NKB + i) * 512);
    b[3] = *(const bf16x8*)(bp + (size_t)(3 * NKB + i) * 512);
}

__global__ __launch_bounds__(64) void k1_mfma(
    const unsigned short* __restrict__ Af, const unsigned short* __restrict__ Bf,
    float* __restrict__ P)
{
    int l = threadIdx.x;
    int wid = blockIdx.x;
    int kseg = wid / 168; int r = wid % 168;
    int c = r / 56; r %= 56;
    int mt = r >> 3, nt = r & 7;
    int kb0 = kseg * 27;

    const unsigned short* ap = Af + ((size_t)(c * NMG + mt * 2) * NKB + kb0) * 512 + l * 8;
    const unsigned short* bp = Bf + ((size_t)(nt * 4) * NKB + kb0) * 512 + l * 8;

    floatx4 acc[2][4];
    #pragma unroll
    for (int mi = 0; mi < 2; ++mi)
        #pragma unroll
        for (int ni = 0; ni < 4; ++ni) acc[mi][ni] = floatx4{0.f, 0.f, 0.f, 0.f};

    bf16x8 a[4][2], b[4][4];
    k1_load(a[0], b[0], ap, bp, 0);
    k1_load(a[1], b[1], ap, bp, 1);
    k1_load(a[2], b[2], ap, bp, 2);
    #pragma unroll
    for (int i = 0; i < 27; ++i) {
        int pf = (i + 3 < 27) ? i + 3 : 26;
        k1_load(a[(i + 3) & 3], b[(i + 3) & 3], ap, bp, pf);
        bf16x8 (&ac)[2] = a[i & 3];
        bf16x8 (&bc)[4] = b[i & 3];
        #pragma unroll
        for (int mi = 0; mi < 2; ++mi)
            #pragma unroll
            for (int ni = 0; ni < 4; ++ni)
                acc[mi][ni] = __builtin_amdgcn_mfma_f32_16x16x32_bf16(ac[mi], bc[ni], acc[mi][ni], 0, 0, 0);
    }
    // epilogue: C/D layout col=l&15, row=(l>>4)*4+reg
    float* Ps = P + (size_t)kseg * WR * QT;
    int lr = l & 15, r0 = (l >> 4) * 4;
    #pragma unroll
    for (int mi = 0; mi < 2; ++mi)
        #pragma unroll
        for (int ni = 0; ni < 4; ++ni) {
            int col = nt * 64 + ni * 16 + lr;
            if (col < NCOL) {
                int q0 = mt * 32 + mi * 16 + r0;
                #pragma unroll
                for (int rr = 0; rr < 4; ++rr)
                    Ps[(size_t)(col * 3 + c) * QT + q0 + rr] = acc[mi][ni][rr];
            }
        }
}

// ---------- K12: fused reduce (blocks < RB) + per-batch prep (blocks >= RB) ----------
constexpr int RB = 158;   // 1440*28 / 256 rounded up
__global__ __launch_bounds__(256) void k12_reduce_prep(
    const float* __restrict__ P,
    const float* __restrict__ beta, const float* __restrict__ theta,
    float* __restrict__ WtF, unsigned short* __restrict__ Wb3,
    unsigned short* __restrict__ xbf, float* __restrict__ RAg, float* __restrict__ tAg)
{
    int t = threadIdx.x;
    if (blockIdx.x < RB) {                     // ---------- reduce path
        int g = blockIdx.x * 256 + t;
        if (g >= WR * 28) return;
        int colc = g / 28, qg = g % 28, q0 = qg * 8;
        float v[8] = {0, 0, 0, 0, 0, 0, 0, 0};
        #pragma unroll
        for (int s = 0; s < KSEG; ++s) {
            const float4* p = (const float4*)(P + ((size_t)s * WR + colc) * QT + q0);
            float4 x0 = p[0], x1 = p[1];
            v[0] += x0.x; v[1] += x0.y; v[2] += x0.z; v[3] += x0.w;
            v[4] += x1.x; v[5] += x1.y; v[6] += x1.z; v[7] += x1.w;
        }
        float4* wp = (float4*)(WtF + (size_t)colc * QT + q0);
        wp[0] = make_float4(v[0], v[1], v[2], v[3]);
        wp[1] = make_float4(v[4], v[5], v[6], v[7]);
        if (colc < NG3 * 16) {                 // Wb3 frag for k3 (zeros for cc in [1368,1408))
            bf16x8 o;
            #pragma unroll
            for (int j = 0; j < 8; ++j)
                o[j] = (short)((colc < MC) ? f2bf(v[j]) : 0);
            int ng3 = colc >> 4, kb3 = q0 >> 5;
            *(bf16x8*)(Wb3 + ((size_t)ng3 * 7 + kb3) * 512
                           + (size_t)((colc & 15) + ((q0 >> 3) & 3) * 16) * 8) = o;
        }
        return;
    }
    // ---------- prep path (one block per batch element)
    int b = blockIdx.x - RB;
    __shared__ float Rs[24][9];
    __shared__ float Jl[24][3];
    __shared__ float resR[24][9];
    __shared__ float rest[24][3];
    __shared__ float bet[10];

    if (t < 10) bet[t] = beta[b * 10 + t];
    if (t < 24) {
        float t0 = theta[b * 72 + t * 3 + 0];
        float t1 = theta[b * 72 + t * 3 + 1];
        float t2 = theta[b * 72 + t * 3 + 2];
        float e0 = t0 + 1e-8f, e1 = t1 + 1e-8f, e2 = t2 + 1e-8f;
        float angle = sqrtf(e0 * e0 + e1 * e1 + e2 * e2);
        float half = 0.5f * angle;
        float sh = sinf(half), ch = cosf(half);
        float s = sh / angle;
        float qx = t0 * s, qy = t1 * s, qz = t2 * s;
        float qn = sqrtf(ch * ch + qx * qx + qy * qy + qz * qz);
        float w = ch / qn, x = qx / qn, y = qy / qn, z = qz / qn;
        Rs[t][0] = 1.f - 2.f * (y * y + z * z);
        Rs[t][1] = 2.f * (x * y - w * z);
        Rs[t][2] = 2.f * (x * z + w * y);
        Rs[t][3] = 2.f * (x * y + w * z);
        Rs[t][4] = 1.f - 2.f * (x * x + z * z);
        Rs[t][5] = 2.f * (y * z - w * x);
        Rs[t][6] = 2.f * (x * z + -w * y);
        Rs[t][7] = 2.f * (y * z + w * x);
        Rs[t][8] = 1.f - 2.f * (x * x + y * y);
    }
    __syncthreads();
    // J from partial sums of P (cols 1368..1439, q in {1, 2..11})
    if (t < 72) {
        int colc = 1368 + t;
        float acc = 0.f;
        #pragma unroll
        for (int s = 0; s < KSEG; ++s)
            acc += P[((size_t)s * WR + colc) * QT + 1];
        #pragma unroll
        for (int n = 0; n < 10; ++n) {
            float cf = 0.f;
            #pragma unroll
            for (int s = 0; s < KSEG; ++s)
                cf += P[((size_t)s * WR + colc) * QT + 2 + n];
            acc += bet[n] * cf;
        }
        Jl[t / 3][t % 3] = acc;
    }
    // x vector in k3 A-fragment layout
    if (t < QT) {
        int q = t;
        float xv = 0.f;
        if (q == 1) xv = 1.f;
        else if (q >= 2 && q < 12) xv = bet[q - 2];
        else if (q >= 12 && q < 219) {
            int p = q - 12;
            int jj = 1 + p / 9, e = p % 9;
            float rr = Rs[jj][e];
            if (e == 0 || e == 4 || e == 8) rr -= 1.f;
            xv = rr;
        }
        int bg = b >> 4, kb3 = q >> 5;
        xbf[((size_t)bg * 7 + kb3) * 512
            + (size_t)((b & 15) + ((q >> 3) & 3) * 16) * 8 + (q & 7)] = f2bf(xv);
    }
    __syncthreads();
    if (t == 0) {
        const int par[24] = {-1,0,0,0,1,2,3,4,5,6,7,8,9,9,9,12,13,14,16,17,18,19,20,21};
        #pragma unroll
        for (int rr = 0; rr < 3; ++rr) {
            resR[0][rr * 3 + 0] =  Rs[0][rr * 3 + 0];
            resR[0][rr * 3 + 1] = -Rs[0][rr * 3 + 1];
            resR[0][rr * 3 + 2] = -Rs[0][rr * 3 + 2];
            rest[0][rr] = Jl[0][rr];
        }
        for (int i = 1; i < 24; ++i) {
            int p = par[i];
            float t0 = Jl[i][0] - Jl[p][0];
            float t1 = Jl[i][1] - Jl[p][1];
            float t2 = Jl[i][2] - Jl[p][2];
            #pragma unroll
            for (int rr = 0; rr < 3; ++rr) {
                float a0 = resR[p][rr * 3 + 0], a1 = resR[p][rr * 3 + 1], a2 = resR[p][rr * 3 + 2];
                resR[i][rr * 3 + 0] = a0 * Rs[i][0] + a1 * Rs[i][3] + a2 * Rs[i][6];
                resR[i][rr * 3 + 1] = a0 * Rs[i][1] + a1 * Rs[i][4] + a2 * Rs[i][7];
                resR[i][rr * 3 + 2] = a0 * Rs[i][2] + a1 * Rs[i][5] + a2 * Rs[i][8];
                rest[i][rr] = a0 * t0 + a1 * t1 + a2 * t2 + rest[p][rr];
            }
        }
    }
    __syncthreads();
    if (t < 216) RAg[(size_t)b * 216 + t] = resR[t / 9][t % 9];
    if (t < 72) {
        int j = t / 3, c = t % 3;
        tAg[(size_t)b * 72 + t] = rest[j][c]
            - (resR[j][c * 3 + 0] * Jl[j][0] + resR[j][c * 3 + 1] * Jl[j][1]
             + resR[j][c * 3 + 2] * Jl[j][2]);
    }
}

// ---------- K3: Mg[b][cc] = sum_q x[b][q] * W[q][cc], register-fragment MFMA ----------
__device__ __forceinline__ void k3_load(bf16x8 (&a)[2], bf16x8 (&b)[4],
    const unsigned short* __restrict__ ap, const unsigned short* __restrict__ bp, int i)
{
    a[0] = *(const bf16x8*)(ap + (size_t)(0 * 7 + i) * 512);
    a[1] = *(const bf16x8*)(ap + (size_t)(1 * 7 + i) * 512);
    b[0] = *(const bf16x8*)(bp + (size_t)(0 * 7 + i) * 512);
    b[1] = *(const bf16x8*)(bp + (size_t)(1 * 7 + i) * 512);
    b[2] = *(const bf16x8*)(bp + (size_t)(2 * 7 + i) * 512);
    b[3] = *(const bf16x8*)(bp + (size_t)(3 * 7 + i) * 512);
}

__global__ __launch_bounds__(256) void k3_mfma(
    const unsigned short* __restrict__ xbf, const unsigned short* __restrict__ Wb3,
    float* __restrict__ Mg)
{
    int w = threadIdx.x >> 6, l = threadIdx.x & 63;
    int wm = w & 1, wn = w >> 1;
    int bt = blockIdx.x / 11, ct = blockIdx.x % 11;
    int bg0 = bt * 4 + wm * 2;
    int ng0 = ct * 8 + wn * 4;

    const unsigned short* ap = xbf + (size_t)bg0 * 7 * 512 + l * 8;
    const unsigned short* bp = Wb3 + (size_t)ng0 * 7 * 512 + l * 8;

    floatx4 acc[2][4];
    #pragma unroll
    for (int mi = 0; mi < 2; ++mi)
        #pragma unroll
        for (int ni = 0; ni < 4; ++ni) acc[mi][ni] = floatx4{0.f, 0.f, 0.f, 0.f};

    bf16x8 a[3][2], b[3][4];
    k3_load(a[0], b[0], ap, bp, 0);
    k3_load(a[1], b[1], ap, bp, 1);
    #pragma unroll
    for (int i = 0; i < 7; ++i) {
        int pf = (i + 2 < 7) ? i + 2 : 6;
        k3_load(a[(i + 2) % 3], b[(i + 2) % 3], ap, bp, pf);
        bf16x8 (&ac)[2] = a[i % 3];
        bf16x8 (&bc)[4] = b[i % 3];
        #pragma unroll
        for (int mi = 0; mi < 2; ++mi)
            #pragma unroll
            for (int ni = 0; ni < 4; ++ni)
                acc[mi][ni] = __builtin_amdgcn_mfma_f32_16x16x32_bf16(ac[mi], bc[ni], acc[mi][ni], 0, 0, 0);
    }
    int lr = l & 15, r0 = (l >> 4) * 4;
    #pragma unroll
    for (int mi = 0; mi < 2; ++mi)
        #pragma unroll
        for (int ni = 0; ni < 4; ++ni) {
            int cc = ct * 128 + wn * 64 + ni * 16 + lr;
            if (cc < MC) {
                int brow = bt * 64 + wm * 32 + mi * 16 + r0;
                #pragma unroll
                for (int rr = 0; rr < 4; ++rr)
                    Mg[(size_t)(brow + rr) * MC + cc] = acc[mi][ni][rr];
            }
        }
}

// ---------- K4: joints[b][k][c] = trans + sum_j RA[c,:].M + tA[c]*w1 ----------
__global__ __launch_bounds__(256) void k4_combine(
    const float* __restrict__ Mg, const float* __restrict__ RAg,
    const float* __restrict__ tAg, const float* __restrict__ WtF,
    const float* __restrict__ trans, float* __restrict__ out)
{
    __shared__ float w1s[456];
    __shared__ float Ms[4 * MC];
    __shared__ float RAs[4 * 216];
    __shared__ float tAs[4 * 72];
    int tid = threadIdx.x;
    int b0 = blockIdx.x * 4;
    for (int i = tid; i < 456; i += 256) w1s[i] = WtF[(size_t)i * 3 * QT];
    for (int i = tid; i < 4 * MC; i += 256) Ms[i] = Mg[(size_t)b0 * MC + i];
    for (int i = tid; i < 4 * 216; i += 256) RAs[i] = RAg[(size_t)b0 * 216 + i];
    for (int i = tid; i < 4 * 72; i += 256) tAs[i] = tAg[(size_t)b0 * 72 + i];
    __syncthreads();
    if (tid < 228) {
        int lb = tid / 57, kc = tid % 57;
        int k = kc / 3, c = kc % 3;
        int b = b0 + lb;
        float acc = trans[b * 3 + c];
        const float* Mrow = Ms + lb * MC;
        const float* RAr  = RAs + lb * 216;
        const float* tAr  = tAs + lb * 72;
        #pragma unroll
        for (int j = 0; j < 24; ++j) {
            int kj = k * 24 + j;
            float m0 = Mrow[kj * 3 + 0], m1 = Mrow[kj * 3 + 1], m2 = Mrow[kj * 3 + 2];
            acc += RAr[j * 9 + c * 3 + 0] * m0
                 + RAr[j * 9 + c * 3 + 1] * m1
                 + RAr[j * 9 + c * 3 + 2] * m2
                 + tAr[j * 3 + c] * w1s[kj];
        }
        out[b * 57 + kc] = acc;
    }
}

extern "C" void kernel_launch(void* const* d_in, const int* in_sizes, int n_in,
                              void* d_out, int out_size, void* d_ws, size_t ws_size,
                              hipStream_t stream)
{
    const float* beta  = (const float*)d_in[0];
    const float* theta = (const float*)d_in[1];
    const float* trans = (const float*)d_in[2];
    const float* vt    = (const float*)d_in[3];
    const float* sdirs = (const float*)d_in[4];
    const float* Jreg  = (const float*)d_in[5];
    const float* pdirs = (const float*)d_in[6];
    const float* jreg  = (const float*)d_in[7];
    const float* wts   = (const float*)d_in[8];
    float* out = (float*)d_out;
    int B = in_sizes[0] / 10;   // 1024

    // workspace layout (~36 MB), all 16B-aligned
    unsigned short* Af  = (unsigned short*)d_ws;                 // 3*14*216*512
    unsigned short* Bf  = Af + (size_t)3 * NMG * NKB * 512;      // 32*216*512
    unsigned short* Wb3 = Bf + (size_t)32 * NKB * 512;           // 88*7*512
    unsigned short* xbf = Wb3 + (size_t)NG3 * 7 * 512;           // 64*7*512
    float* P   = (float*)(xbf + (size_t)64 * 7 * 512);           // KSEG*WR*QT
    float* WtF = P + (size_t)KSEG * WR * QT;                     // WR*QT
    float* RAg = WtF + (size_t)WR * QT;                          // B*216
    float* tAg = RAg + (size_t)B * 216;                          // B*72
    float* Mg  = tAg + (size_t)B * 72;                           // B*MC

    k0_build<<<dim3(QT * 27 + 108), 256, 0, stream>>>(
        vt, sdirs, pdirs, Jreg, jreg, wts, Af, Bf);
    k1_mfma<<<dim3(168 * KSEG), 64, 0, stream>>>(Af, Bf, P);
    k12_reduce_prep<<<dim3(RB + B), 256, 0, stream>>>(
        P, beta, theta, WtF, Wb3, xbf, RAg, tAg);
    k3_mfma<<<dim3((B / 64) * 11), 256, 0, stream>>>(xbf, Wb3, Mg);
    k4_combine<<<dim3(B / 4), 256, 0, stream>>>(Mg, RAg, tAg, WtF, trans, out);
}